// Round 11
// baseline (11297.481 us; speedup 1.0000x reference)
//
#include <hip/hip_runtime.h>

// ============================================================================
// 2-layer LSTM (B=256, T=1024, H=512, in=1) + linear head. fp32 in/out.
//
// R15 (from R11 @9.66ms; R12-R14 all regressed): FUSE L0+L1 into ONE WG set.
// 64 WGs/chunk x 8 units of BOTH layers (Wh0+Wx1+Wh1 = 96KB LDS).
// Iteration k: fill p_k ONCE -> feeds L0 MFMA (p_{k+1}) AND L1 ph2 (q_k).
//  order: poll pf(k) -> fill p_k -> L0 MFMA -> publish p_{k+1} ASAP ->
//         ph2 (+held ph1) -> q_k epilogue/store/flag -> head ->
//         poll qf(k) -> fill q_k -> ph1 for k+1 (held acc).
// Wins vs R11 topology: L1's separate p-wait leg deleted (shared fill);
// q-exchange latency hidden at iteration end (next p already published by
// peers mid-iteration); BOTH ring guards provably free (pf>=k+1 implies
// peers consumed p_{k-1} >> p_{k-15}; qf>=k implies q_{k-16} consumed).
// Protocol primitives unchanged (R7/R11-verified): per-line flags, 64-lane
// polls, LDS stage + coop full-line st8 stores, drain(barrier)->flag,
// epoch buffer_inv sc1, hi/lo fp16 transport, deferred head atomic.
// Math bit-identical to R11 (ph1-then-ph2, kt ascending; same epilogue) ->
// absmax 6.103516e-05 expected exact.
// Predicted: 4.5-6.5ms, MfmaUtil 20-27, VGPR 190-230 (spill sig: 256 +
// WRITE>>1.4GB -> revert), FETCH ~1.2GB. Hang => flag-order bug.
// ============================================================================

typedef _Float16 f16;
typedef _Float16 f16x8 __attribute__((ext_vector_type(8)));
typedef float f32x4 __attribute__((ext_vector_type(4)));
typedef unsigned long long u64;

#define NB 256
#define NT_ 1024
#define NH 512
#define RING 16
#define SLOT (NB * NH)    // 131072 elems per ring slot

__device__ __forceinline__ float sigm(float x)  { return 1.0f / (1.0f + __expf(-x)); }
__device__ __forceinline__ float tanhx(float x) { return 2.0f / (1.0f + __expf(-2.0f * x)) - 1.0f; }

// 8B agent-visible write-through store (verified R3..R11 transport primitive)
__device__ __forceinline__ void st8(unsigned short* p, u64 v) {
  __hip_atomic_store((u64*)p, v, __ATOMIC_RELAXED, __HIP_MEMORY_SCOPE_AGENT);
}
__device__ __forceinline__ void stf(unsigned* p, unsigned v) {
  __hip_atomic_store(p, v, __ATOMIC_RELAXED, __HIP_MEMORY_SCOPE_AGENT);
}
__device__ __forceinline__ unsigned ldf(const unsigned* p) {
  return __hip_atomic_load(p, __ATOMIC_RELAXED, __HIP_MEMORY_SCOPE_AGENT);
}
// Poll until every lane's flag (per-lane address) reaches thr.
__device__ __forceinline__ void pollr(const unsigned* a, unsigned thr) {
  for (;;) {
    unsigned v = ldf(a);
    if (!~__ballot(v >= thr)) break;
    __builtin_amdgcn_s_sleep(1);
  }
  asm volatile("" ::: "memory");
}

// ---------------------------------------------------------------------------
__global__ void prep_xT(const float* __restrict__ inp, float* __restrict__ xT) {
  int g = blockIdx.x * 256 + threadIdx.x;
  int t = g >> 8, b = g & 255;
  xT[t * NB + b] = inp[b * NT_ + t];
}

// ---------------------------------------------------------------------------
// fp32 -> fp16 weights, UNIFIED 8-unit tiling for all 3 matrices:
// 64 slices x [jt<2][kt<16][lane<64][j<8]; slice = 16384 elems.
// gcol = (jt*2+(cl>>3))*512 + sl*8 + (cl&7);  k = kt*32 + qd*8 + j.
__global__ void prep_w(const float* __restrict__ Wh0,
                       const float* __restrict__ Wx1,
                       const float* __restrict__ Wh1,
                       f16* __restrict__ dst) {
  int g = blockIdx.x * 256 + threadIdx.x;   // 3 * 2^20 threads
  int mat = g >> 20;
  int r = g & 0xFFFFF;
  int j = r & 7, ln = (r >> 3) & 63, kt = (r >> 9) & 15;
  int jt = (r >> 13) & 1, sl = (r >> 14) & 63;
  int cl = ln & 15, qd = ln >> 4;
  int k = kt * 32 + qd * 8 + j;
  const float* W = (mat == 0) ? Wh0 : (mat == 1) ? Wx1 : Wh1;
  int gcol = (jt * 2 + (cl >> 3)) * 512 + sl * 8 + (cl & 7);
  size_t di = (size_t)mat * 1048576 + (size_t)sl * 16384 +
              (((size_t)jt * 16 + kt) * 64 + ln) * 8 + j;
  dst[di] = (f16)W[(size_t)k * 2048 + gcol];
}

// ---------------------------------------------------------------------------
__global__ void reduce_out(const float* __restrict__ part8,
                           const float* __restrict__ bfp,
                           float* __restrict__ out) {
  int g = blockIdx.x * 256 + threadIdx.x;   // 262144 = b*1024+t
  float v = bfp[0];
#pragma unroll
  for (int j = 0; j < 8; ++j) v += part8[(size_t)j * (NB * NT_) + g];
  out[g] = v;
}

// ---------------------------------------------------------------------------
// h transport (slice-major, per-WG-contiguous 1KB blocks):
//   p[slot][c<4][sl<64][row<64][unit<8]   (elem = slot*131072 + c*32768
//   q[slot][c<4][sl<64][row<64][unit<8]    + sl*512 + row*8 + unit)
// A-fragment for kt: global unit g = kt*32 + qd*8 + j -> slice kt*4+qd,
// offset j -> ONE b128 per fragment per stream.
__global__ __launch_bounds__(256, 1) void lstm_main(
    const float* __restrict__ xT,       // [T][B]
    const f16*  __restrict__ wsl,       // tiled fp16 weights (6 MB)
    const float* __restrict__ wx0,      // [2048]
    const float* __restrict__ bias0,    // [2048]
    const float* __restrict__ bias1,    // [2048]
    const float* __restrict__ wf,       // [512]
    unsigned short* p_hi, unsigned short* p_lo,   // [RING][...]
    unsigned short* q_hi, unsigned short* q_lo,   // [RING][...]
    unsigned int* pf,                   // [4c][64sl] one 128B line each
    unsigned int* qf,                   // [4c][64sl] one 128B line each
    float* part8)                       // [8][B][T]
{
  extern __shared__ char smem[];
  const int tid = threadIdx.x;
  const int wv = tid >> 6, ln = tid & 63;
  const int qd = ln >> 4, cl = ln & 15;
  const int bx = blockIdx.x;
  const int c = bx & 3, sl = bx >> 2;   // chunk, slice(0..63)
  const float LO = 1.0f / 1024.0f;
  const int u = cl & 7, g01 = cl >> 3;
  const bool hiH = (cl < 8);
  const int lr = wv * 16 + cl;          // chunk-local A row

  // ---- stage 3 weight slices into LDS (96 KB) ----
  {
    const int4* s0 = (const int4*)wsl + (size_t)sl * 2048;            // Wh0
    const int4* s1 = (const int4*)wsl + 131072 + (size_t)sl * 2048;   // Wx1
    const int4* s2 = (const int4*)wsl + 262144 + (size_t)sl * 2048;   // Wh1
    int4* d = (int4*)smem;
    for (int i = tid; i < 2048; i += 256) {
      d[i] = s0[i]; d[2048 + i] = s1[i]; d[4096 + i] = s2[i];
    }
  }
  __syncthreads();
  const f16x8* wh0_ = (const f16x8*)smem;
  const f16x8* wx1_ = (const f16x8*)(smem + 32768);
  const f16x8* wh1_ = (const f16x8*)(smem + 65536);
  f16* shp = (f16*)(smem + 98304);      // p stage hi [64][8] (1 KB)
  f16* slp = shp + 512;                 // p stage lo
  f16* shq = shp + 1024;                // q stage hi
  f16* slq = shp + 1536;                // q stage lo

  // loop-invariant per-lane constants (unit = sl*8 + u)
  float w0a, w0b, b0a, b0b, b1a, b1b, wfv;
  {
    int base = sl * 8 + u;
    w0a = wx0[g01 * 512 + base];        b0a = bias0[g01 * 512 + base];
    w0b = wx0[(2 + g01) * 512 + base];  b0b = bias0[(2 + g01) * 512 + base];
    b1a = bias1[g01 * 512 + base];      b1b = bias1[(2 + g01) * 512 + base];
    wfv = wf[base];
  }
  float cst0[4] = {0.f,0.f,0.f,0.f}, cst1[4] = {0.f,0.f,0.f,0.f};
  const f32x4 z4 = (f32x4){0.f,0.f,0.f,0.f};
  f32x4 aq[2], aqL[2];                  // held ph1 acc (q_{k-1}@Wh1)
  aq[0] = z4; aq[1] = z4; aqL[0] = z4; aqL[1] = z4;
  unsigned* pfl_me = pf + (c * 64 + sl) * 32;
  unsigned* qfl_me = qf + (c * 64 + sl) * 32;
  const unsigned* pfl_all = pf + (c * 64 + ln) * 32;
  const unsigned* qfl_all = qf + (c * 64 + ln) * 32;

  // ---- prologue: p_0 = LSTM0(x_0, 0) -> store slot 0, pf=1 ----
  {
    float4 xv = *(const float4*)(xT + c * 64 + wv * 16 + qd * 4);
#pragma unroll
    for (int e = 0; e < 4; ++e) {
      float xe = (e == 0) ? xv.x : (e == 1) ? xv.y : (e == 2) ? xv.z : xv.w;
      float v0 = xe * w0a + b0a;
      float v1 = xe * w0b + b0b;
      float s0_ = __shfl_xor(v0, 8, 16);
      float s1_ = __shfl_xor(v1, 8, 16);
      float gi = hiH ? v0 : s0_;
      float gf = hiH ? s0_ : v0;
      float gg = hiH ? v1 : s1_;
      float go = hiH ? s1_ : v1;
      float ii = sigm(gi), ff = sigm(gf), tg = tanhx(gg), oo = sigm(go);
      (void)ff;
      cst0[e] = ii * tg;                // f*c_{-1} = 0
      float h = oo * tanhx(cst0[e]);
      f16 hh = (f16)h;
      int su = (wv * 16 + qd * 4 + e) * 8 + u;
      if (hiH) shp[su] = hh;
      else     slp[su] = (f16)((h - (float)hh) * 1024.0f);
    }
    __syncthreads();
    {
      unsigned short* bh = p_hi + (size_t)c * 32768 + (size_t)sl * 512;
      unsigned short* bl = p_lo + (size_t)c * 32768 + (size_t)sl * 512;
      int strm = tid >> 7, pc = tid & 127;
      const f16* src = (strm ? slp : shp) + pc * 4;
      st8((strm ? bl : bh) + pc * 4, *(const u64*)src);
    }
    __syncthreads();   // stores vmcnt-drained at LLC
    if (tid == 0) stf(pfl_me, 1u);
  }

  // ---- main loop: iteration k consumes p_k, produces p_{k+1} and q_k ----
  for (int k = 0; k < NT_; ++k) {
    if ((k & (RING - 1)) == 0 && k) {
      __syncthreads();
      if (wv == 0)
        asm volatile("buffer_inv sc1\n\ts_waitcnt vmcnt(0)" ::: "memory");
      __syncthreads();
    }
    const int sp_r = k & (RING - 1);
    const int sp_w = (k + 1) & (RING - 1);
    const int sq_w = k & (RING - 1);
    // x_{k+1} prefetch (clamped at the tail; p_1024 is never consumed)
    int xs = (k + 1 < NT_) ? (k + 1) : (NT_ - 1);
    float4 xv = *(const float4*)(xT + (size_t)xs * NB + c * 64 + wv * 16 + qd * 4);
    // wait p_k available (pf >= k+1; prologue seeded 1)
    pollr(pfl_all, (unsigned)(k + 1));
    // ---- fill p_k (shared by L0 MFMA and L1 ph2): 32 b128, batched ----
    const f16* ah = (const f16*)p_hi + (size_t)sp_r * SLOT + (size_t)c * 32768 + qd * 512 + lr * 8;
    const f16* al = (const f16*)p_lo + (size_t)sp_r * SLOT + (size_t)c * 32768 + qd * 512 + lr * 8;
    f16x8 Ap[16], ApL[16];
#pragma unroll
    for (int kt = 0; kt < 16; ++kt) {
      Ap[kt]  = *(const f16x8*)(ah + kt * 2048);
      ApL[kt] = *(const f16x8*)(al + kt * 2048);
    }
    // ---- L0: p_k @ Wh0-slice ----
    f32x4 a0[2], a0L[2];
    a0[0] = z4; a0[1] = z4; a0L[0] = z4; a0L[1] = z4;
#pragma unroll
    for (int kt = 0; kt < 16; ++kt) {
#pragma unroll
      for (int jt = 0; jt < 2; ++jt) {
        f16x8 bw = wh0_[(jt * 16 + kt) * 64 + ln];
        a0[jt]  = __builtin_amdgcn_mfma_f32_16x16x32_f16(Ap[kt],  bw, a0[jt],  0, 0, 0);
        a0L[jt] = __builtin_amdgcn_mfma_f32_16x16x32_f16(ApL[kt], bw, a0L[jt], 0, 0, 0);
      }
    }
    // ---- L0 epilogue -> stage -> publish p_{k+1} ASAP (cycle-critical) ----
#pragma unroll
    for (int e = 0; e < 4; ++e) {
      float xe = (e == 0) ? xv.x : (e == 1) ? xv.y : (e == 2) ? xv.z : xv.w;
      float v0 = a0[0][e] + a0L[0][e] * LO + xe * w0a + b0a;   // i / f
      float v1 = a0[1][e] + a0L[1][e] * LO + xe * w0b + b0b;   // g / o
      float s0_ = __shfl_xor(v0, 8, 16);
      float s1_ = __shfl_xor(v1, 8, 16);
      float gi = hiH ? v0 : s0_;
      float gf = hiH ? s0_ : v0;
      float gg = hiH ? v1 : s1_;
      float go = hiH ? s1_ : v1;
      float ii = sigm(gi), ff = sigm(gf), tg = tanhx(gg), oo = sigm(go);
      cst0[e] = ff * cst0[e] + ii * tg;
      float h = oo * tanhx(cst0[e]);
      f16 hh = (f16)h;
      int su = (wv * 16 + qd * 4 + e) * 8 + u;
      if (hiH) shp[su] = hh;
      else     slp[su] = (f16)((h - (float)hh) * 1024.0f);
    }
    __syncthreads();
    {
      unsigned short* bh = p_hi + (size_t)sp_w * SLOT + (size_t)c * 32768 + (size_t)sl * 512;
      unsigned short* bl = p_lo + (size_t)sp_w * SLOT + (size_t)c * 32768 + (size_t)sl * 512;
      int strm = tid >> 7, pc = tid & 127;
      const f16* src = (strm ? slp : shp) + pc * 4;
      st8((strm ? bl : bh) + pc * 4, *(const u64*)src);
    }
    __syncthreads();   // stores vmcnt-drained at LLC
    if (tid == 0) stf(pfl_me, (unsigned)(k + 2));
    // ---- L1 ph2: p_k @ Wx1-slice, accumulated into held ph1 ----
#pragma unroll
    for (int kt = 0; kt < 16; ++kt) {
#pragma unroll
      for (int jt = 0; jt < 2; ++jt) {
        f16x8 bw = wx1_[(jt * 16 + kt) * 64 + ln];
        aq[jt]  = __builtin_amdgcn_mfma_f32_16x16x32_f16(Ap[kt],  bw, aq[jt],  0, 0, 0);
        aqL[jt] = __builtin_amdgcn_mfma_f32_16x16x32_f16(ApL[kt], bw, aqL[jt], 0, 0, 0);
      }
    }
    // ---- L1 epilogue -> q_k stage/store/flag ----
    float po[4];
#pragma unroll
    for (int e = 0; e < 4; ++e) {
      float v0 = aq[0][e] + aqL[0][e] * LO + b1a;   // i / f
      float v1 = aq[1][e] + aqL[1][e] * LO + b1b;   // g / o
      float s0_ = __shfl_xor(v0, 8, 16);
      float s1_ = __shfl_xor(v1, 8, 16);
      float gi = hiH ? v0 : s0_;
      float gf = hiH ? s0_ : v0;
      float gg = hiH ? v1 : s1_;
      float go = hiH ? s1_ : v1;
      float ii = sigm(gi), ff = sigm(gf), tg = tanhx(gg), oo = sigm(go);
      cst1[e] = ff * cst1[e] + ii * tg;
      float h = oo * tanhx(cst1[e]);
      f16 hh = (f16)h;
      int su = (wv * 16 + qd * 4 + e) * 8 + u;
      if (hiH) shq[su] = hh;
      else     slq[su] = (f16)((h - (float)hh) * 1024.0f);
      po[e] = hiH ? wfv * h : 0.0f;
    }
    __syncthreads();
    {
      unsigned short* bh = q_hi + (size_t)sq_w * SLOT + (size_t)c * 32768 + (size_t)sl * 512;
      unsigned short* bl = q_lo + (size_t)sq_w * SLOT + (size_t)c * 32768 + (size_t)sl * 512;
      int strm = tid >> 7, pc = tid & 127;
      const f16* src = (strm ? slq : shq) + pc * 4;
      st8((strm ? bl : bh) + pc * 4, *(const u64*)src);
    }
    __syncthreads();   // stores vmcnt-drained at LLC
    if (tid == 0) stf(qfl_me, (unsigned)(k + 1));
    // ---- deferred head output (off critical path) ----
#pragma unroll
    for (int e = 0; e < 4; ++e) {
      float r = po[e];
#pragma unroll
      for (int m = 1; m < 16; m <<= 1) r += __shfl_xor(r, m, 16);
      if (cl == 0)
        atomicAdd(part8 + (size_t)(sl & 7) * (NB * NT_) +
                      (size_t)(c * 64 + wv * 16 + qd * 4 + e) * NT_ + k, r);
    }
    // ---- ph1 for k+1: q_k @ Wh1-slice (held; q-latency hidden here) ----
    if (k + 1 < NT_) {
      pollr(qfl_all, (unsigned)(k + 1));
      const f16* bqh = (const f16*)q_hi + (size_t)sq_w * SLOT + (size_t)c * 32768 + qd * 512 + lr * 8;
      const f16* bql = (const f16*)q_lo + (size_t)sq_w * SLOT + (size_t)c * 32768 + qd * 512 + lr * 8;
      f16x8 Aq_[16], AqL_[16];
#pragma unroll
      for (int kt = 0; kt < 16; ++kt) {
        Aq_[kt]  = *(const f16x8*)(bqh + kt * 2048);
        AqL_[kt] = *(const f16x8*)(bql + kt * 2048);
      }
      aq[0] = z4; aq[1] = z4; aqL[0] = z4; aqL[1] = z4;
#pragma unroll
      for (int kt = 0; kt < 16; ++kt) {
#pragma unroll
        for (int jt = 0; jt < 2; ++jt) {
          f16x8 bw = wh1_[(jt * 16 + kt) * 64 + ln];
          aq[jt]  = __builtin_amdgcn_mfma_f32_16x16x32_f16(Aq_[kt],  bw, aq[jt],  0, 0, 0);
          aqL[jt] = __builtin_amdgcn_mfma_f32_16x16x32_f16(AqL_[kt], bw, aqL[jt], 0, 0, 0);
        }
      }
    }
  }
}

// ---------------------------------------------------------------------------
extern "C" void kernel_launch(void* const* d_in, const int* in_sizes, int n_in,
                              void* d_out, int out_size, void* d_ws, size_t ws_size,
                              hipStream_t stream) {
  (void)in_sizes; (void)n_in; (void)out_size; (void)ws_size;
  const float* inp = (const float*)d_in[0];
  const float* Wx0 = (const float*)d_in[1];
  const float* Wh0 = (const float*)d_in[2];
  const float* b0  = (const float*)d_in[3];
  const float* Wx1 = (const float*)d_in[4];
  const float* Wh1 = (const float*)d_in[5];
  const float* b1  = (const float*)d_in[6];
  const float* Wf  = (const float*)d_in[7];
  const float* bf  = (const float*)d_in[8];

  const size_t MB = 1u << 20;
  const size_t OFF_W    = 0;                 // 6 MiB tiled fp16 weights
  const size_t OFF_XT   = 6 * MB;            // 1 MiB
  const size_t OFF_PHI  = 7 * MB;            // 4 MiB (RING x 256 KB)
  const size_t OFF_PLO  = 11 * MB;
  const size_t OFF_QHI  = 15 * MB;
  const size_t OFF_QLO  = 19 * MB;
  const size_t OFF_PART = 23 * MB;           // 8 MiB
  const size_t OFF_CTR  = 31 * MB;           // flags: pf 32KB + qf 32KB

  char* ws = (char*)d_ws;
  f16* wsl = (f16*)(ws + OFF_W);
  float* xT = (float*)(ws + OFF_XT);
  unsigned short* phi = (unsigned short*)(ws + OFF_PHI);
  unsigned short* plo = (unsigned short*)(ws + OFF_PLO);
  unsigned short* qhi = (unsigned short*)(ws + OFF_QHI);
  unsigned short* qlo = (unsigned short*)(ws + OFF_QLO);
  float* part8 = (float*)(ws + OFF_PART);
  unsigned int* pfl = (unsigned int*)(ws + OFF_CTR);
  unsigned int* qfl = pfl + 8192;            // pf = 256 lines * 32 u32 = 32KB
  float* out = (float*)d_out;

  (void)hipFuncSetAttribute((const void*)lstm_main,
                            hipFuncAttributeMaxDynamicSharedMemorySize, 102400);

  // zero rings + partials + flags (contiguous; flags 64 KB)
  (void)hipMemsetAsync(ws + OFF_PHI, 0, (OFF_CTR + 65536) - OFF_PHI, stream);

  prep_xT<<<1024, 256, 0, stream>>>(inp, xT);
  prep_w<<<12288, 256, 0, stream>>>(Wh0, Wx1, Wh1, wsl);

  lstm_main<<<256, 256, 102400, stream>>>(xT, wsl, Wx0, b0, b1, Wf,
                                          phi, plo, qhi, qlo, pfl, qfl, part8);

  reduce_out<<<1024, 256, 0, stream>>>(part8, bf, out);
}

// Round 12
// 9878.667 us; speedup vs baseline: 1.1436x; 1.1436x over previous
//
#include <hip/hip_runtime.h>

// ============================================================================
// 2-layer LSTM (B=256, T=1024, H=512, in=1) + linear head. fp32 in/out.
//
// R16 = R11 topology (verified 9.66ms) + PARITY-TAGGED FLAGLESS TRANSPORT.
// Evidence (R5..R15): only latency-leg removal helps (R7 -21%); R11 chain
// still pays detect RT + drain + flag-publish RT because data & readiness
// are separate objects. Fix: data self-validates.
//  - Producer of step s forces bit0 of EVERY stored u16 (hi and lo fp16
//    streams) to epoch parity (s>>4)&1. lo is computed AFTER forcing hi ->
//    compensates exactly; residual error <= 2^-21 (absmax may rise slightly).
//  - Consumer fill = agent-scope 8B loads + retry until all words carry the
//    expected parity. Slot reuse (RING=16) flips parity; init sentinel
//    (memset 0xFF, parity 1) differs from epoch-0 parity 0. Stale data and
//    not-yet-written both detectable per word.
//  - DELETED: data flags, producer vmcnt drains, consumer detect polls,
//    epoch buffer_inv (agent loads are LLC-fresh), one of two barriers
//    (stage LDS double-buffered by s&1).
//  - Overwrite guards: L0-peers & L1-peers self-proving (validated step-s-1
//    load => producer consumed s-2 => all older consumed). Only L0-vs-L1
//    needs a counter: L1 publishes consumed-step (fire-forget, 1 line/WG)
//    once/step; L0 checks >= s-8 once per 8 steps (slack 8 < RING).
// Chain/step (L1 pacer): fill-q(RT) + ph1 + fill-p(RT, ready) + ph2 + epi
// + store-issue ~= 2RT + 3us  (vs R11 ~4RT + 3us).
// Predicted: 6-7.5ms, MfmaUtil 17-20, VGPR 180-220, absmax <= ~1.5e-4.
// Hang => protocol bug. Neutral => declare latency floor.
// ============================================================================

typedef _Float16 f16;
typedef _Float16 f16x8 __attribute__((ext_vector_type(8)));
typedef float f32x4 __attribute__((ext_vector_type(4)));
typedef unsigned long long u64;
typedef unsigned long long u64x2 __attribute__((ext_vector_type(2)));
typedef unsigned short u16;

#define NB 256
#define NT_ 1024
#define NH 512
#define RING 16
#define SLOT (NB * NH)
#define PMASK 0x0001000100010001ull

__device__ __forceinline__ float sigm(float x)  { return 1.0f / (1.0f + __expf(-x)); }
__device__ __forceinline__ float tanhx(float x) { return 2.0f / (1.0f + __expf(-2.0f * x)) - 1.0f; }

// agent-scope primitives (verified R3..R11)
__device__ __forceinline__ void st8(u16* p, u64 v) {
  __hip_atomic_store((u64*)p, v, __ATOMIC_RELAXED, __HIP_MEMORY_SCOPE_AGENT);
}
__device__ __forceinline__ u64 ld8a(const u16* p) {
  return __hip_atomic_load((const u64*)p, __ATOMIC_RELAXED, __HIP_MEMORY_SCOPE_AGENT);
}
__device__ __forceinline__ void stf(unsigned* p, unsigned v) {
  __hip_atomic_store(p, v, __ATOMIC_RELAXED, __HIP_MEMORY_SCOPE_AGENT);
}
__device__ __forceinline__ unsigned ldf(const unsigned* p) {
  return __hip_atomic_load(p, __ATOMIC_RELAXED, __HIP_MEMORY_SCOPE_AGENT);
}
__device__ __forceinline__ void pollr(const unsigned* a, unsigned thr) {
  for (;;) {
    unsigned v = ldf(a);
    if (!~__ballot(v >= thr)) break;
    __builtin_amdgcn_s_sleep(1);
  }
  asm volatile("" ::: "memory");
}
__device__ __forceinline__ f16x8 frag(u64 w0, u64 w1) {
  u64x2 t; t.x = w0; t.y = w1;
  return __builtin_bit_cast(f16x8, t);
}

// ---------------------------------------------------------------------------
__global__ void prep_xT(const float* __restrict__ inp, float* __restrict__ xT) {
  int g = blockIdx.x * 256 + threadIdx.x;
  int t = g >> 8, b = g & 255;
  xT[t * NB + b] = inp[b * NT_ + t];
}

// ---------------------------------------------------------------------------
// fp32 -> fp16 weights, unified tiling (verified R11): 32 slices x
// [nh<2][jt<2][kt<16][lane<64][j<8]; slice = 32768 elems.
__global__ void prep_w(const float* __restrict__ Wh0,
                       const float* __restrict__ Wx1,
                       const float* __restrict__ Wh1,
                       f16* __restrict__ dst) {
  int g = blockIdx.x * 256 + threadIdx.x;   // 3 * 2^20 threads
  int mat = g >> 20;
  int r = g & 0xFFFFF;
  int j = r & 7, ln = (r >> 3) & 63, kt = (r >> 9) & 15;
  int cl = ln & 15, qd = ln >> 4;
  int k = kt * 32 + qd * 8 + j;
  int jt = (r >> 13) & 1, nh = (r >> 14) & 1, sl = (r >> 15) & 31;
  const float* W = (mat == 0) ? Wh0 : (mat == 1) ? Wx1 : Wh1;
  int gate = jt * 2 + (cl >> 3);
  int gcol = gate * 512 + sl * 16 + nh * 8 + (cl & 7);
  size_t di = (size_t)mat * 1048576 + (size_t)sl * 32768 +
              (((size_t)(nh * 2 + jt) * 16 + kt) * 64 + ln) * 8 + j;
  dst[di] = (f16)W[(size_t)k * 2048 + gcol];
}

// ---------------------------------------------------------------------------
__global__ void reduce_out(const float* __restrict__ part8,
                           const float* __restrict__ bfp,
                           float* __restrict__ out) {
  int g = blockIdx.x * 256 + threadIdx.x;   // 262144 = b*1024+t
  float v = bfp[0];
#pragma unroll
  for (int j = 0; j < 8; ++j) v += part8[(size_t)j * (NB * NT_) + g];
  out[g] = v;
}

// ---------------------------------------------------------------------------
// h transport (slice-major; R7/R11-verified layout), PARITY-TAGGED:
//   p[slot][c<4][sl<32][row<64][unit<16]  q[slot][c<4][sl<32][row<64][unit<16]
// every u16 carries epoch parity (step>>4)&1 in bit0. Buffers init 0xFF.
__global__ __launch_bounds__(256, 1) void lstm_main(
    const float* __restrict__ xT,       // [T][B]
    const f16*  __restrict__ wsl,       // tiled fp16 weights (6 MB)
    const float* __restrict__ wx0,      // [2048]
    const float* __restrict__ bias0,    // [2048]
    const float* __restrict__ bias1,    // [2048]
    const float* __restrict__ wf,       // [512]
    u16* p_hi, u16* p_lo,               // [RING][...]
    u16* q_hi, u16* q_lo,               // [RING][...]
    unsigned int* prog,                 // [4c][32 WG] x 32 u32 (1 line each)
    float* part8)                       // [8][B][T]
{
  extern __shared__ char smem[];
  const int tid = threadIdx.x;
  const int wv = tid >> 6, ln = tid & 63;
  const int qd = ln >> 4, cl = ln & 15;
  const int bx = blockIdx.x;
  const int r8 = bx & 7, idx = bx >> 3;
  const bool isL0 = !(r8 & 1);
  const int c = r8 >> 1;
  const int sl = idx;                   // 0..31 both layers
  const float LO = 1.0f / 1024.0f;
  const int u = cl & 7, g01 = cl >> 3;
  const bool hiH = (cl < 8);
  const int lr = wv * 16 + cl;          // chunk-local A row

  // ---- stage weight slice(s) into LDS (once) ----
  if (isL0) {
    const int4* s0 = (const int4*)wsl + (size_t)sl * 4096;           // 64 KB
    int4* d = (int4*)smem;
    for (int i = tid; i < 4096; i += 256) d[i] = s0[i];
  } else {
    const int4* s1 = (const int4*)wsl + 131072 + (size_t)sl * 4096;  // Wx1 64 KB
    const int4* s2 = (const int4*)wsl + 262144 + (size_t)sl * 4096;  // Wh1 64 KB
    int4* d = (int4*)smem;
    for (int i = tid; i < 4096; i += 256) { d[i] = s1[i]; d[4096 + i] = s2[i]; }
  }
  __syncthreads();

  unsigned* progc = prog + c * 32 * 32;           // chunk's 32 lines

  if (isL0) {
    // ======== layer 0: p_s = LSTM(x_s, p_{s-1}) ========
    float w0a[2], w0b[2], b0a[2], b0b[2];
#pragma unroll
    for (int nh = 0; nh < 2; ++nh) {
      int base = sl * 16 + nh * 8 + u;
      w0a[nh] = wx0[g01 * 512 + base];
      b0a[nh] = bias0[g01 * 512 + base];
      w0b[nh] = wx0[(2 + g01) * 512 + base];
      b0b[nh] = bias0[(2 + g01) * 512 + base];
    }
    float cst[2][4] = {{0.f,0.f,0.f,0.f},{0.f,0.f,0.f,0.f}};
    const unsigned* pga = progc + (ln & 31) * 32;   // guard lines (dup ok)
    const f16x8* wl = (const f16x8*)smem;

    for (int s = 0; s < NT_; ++s) {
      // amortized L1-consumption guard: once per 8 steps
      if (s >= 16 && (s & 7) == 0) pollr(pga, (unsigned)(s - 8));
      const int slot_r = (s + RING - 1) & (RING - 1);   // p_{s-1}
      const int slot_w = s & (RING - 1);                // p_s
      float4 xv = *(const float4*)(xT + s * NB + c * 64 + wv * 16 + qd * 4);
      f32x4 acc[4], accL[4];
#pragma unroll
      for (int t4 = 0; t4 < 4; ++t4) {
        acc[t4] = (f32x4){0.f,0.f,0.f,0.f};
        accL[t4] = (f32x4){0.f,0.f,0.f,0.f};
      }
      if (s) {
        // ---- self-validating fill of p_{s-1} (parity ((s-1)>>4)&1) ----
        const u16* ah = (const u16*)p_hi + (size_t)slot_r * SLOT + (size_t)c * 32768 +
                        (qd >> 1) * 1024 + lr * 16 + (qd & 1) * 8;
        const u16* al = (const u16*)p_lo + (size_t)slot_r * SLOT + (size_t)c * 32768 +
                        (qd >> 1) * 1024 + lr * 16 + (qd & 1) * 8;
        const u64 want = (((s - 1) >> 4) & 1) ? PMASK : 0ull;
        u64 wh_a[32], wl_a[32];
        for (;;) {
#pragma unroll
          for (int kt = 0; kt < 16; ++kt) {
            wh_a[2*kt]   = ld8a(ah + kt * 2048);
            wh_a[2*kt+1] = ld8a(ah + kt * 2048 + 4);
            wl_a[2*kt]   = ld8a(al + kt * 2048);
            wl_a[2*kt+1] = ld8a(al + kt * 2048 + 4);
          }
          bool ok = true;
#pragma unroll
          for (int i = 0; i < 32; ++i)
            ok &= ((wh_a[i] & PMASK) == want) & ((wl_a[i] & PMASK) == want);
          if (!~__ballot(ok)) break;
          __builtin_amdgcn_s_sleep(1);
        }
        asm volatile("" ::: "memory");
#pragma unroll
        for (int kt = 0; kt < 16; ++kt) {
          f16x8 Ah = frag(wh_a[2*kt], wh_a[2*kt+1]);
          f16x8 Al = frag(wl_a[2*kt], wl_a[2*kt+1]);
#pragma unroll
          for (int t4 = 0; t4 < 4; ++t4) {               // t4 = nh*2 + jt
            f16x8 bw = wl[(t4 * 16 + kt) * 64 + ln];
            acc[t4]  = __builtin_amdgcn_mfma_f32_16x16x32_f16(Ah, bw, acc[t4], 0, 0, 0);
            accL[t4] = __builtin_amdgcn_mfma_f32_16x16x32_f16(Al, bw, accL[t4], 0, 0, 0);
          }
        }
      }
      // ---- epilogue (shfl-swap) -> double-buffered LDS stage, parity-forced ----
      u16* shp = (u16*)(smem + 65536) + (s & 1) * 2048;  // [64][16] hi
      u16* slp = shp + 1024;                             // [64][16] lo
      const u16 P = (u16)((s >> 4) & 1);
#pragma unroll
      for (int e = 0; e < 4; ++e) {
        float xe = (e == 0) ? xv.x : (e == 1) ? xv.y : (e == 2) ? xv.z : xv.w;
        int r = wv * 16 + qd * 4 + e;
#pragma unroll
        for (int nh = 0; nh < 2; ++nh) {
          float v0 = acc[nh*2+0][e] + accL[nh*2+0][e] * LO + xe * w0a[nh] + b0a[nh];
          float v1 = acc[nh*2+1][e] + accL[nh*2+1][e] * LO + xe * w0b[nh] + b0b[nh];
          float w0 = __shfl_xor(v0, 8, 16);
          float w1 = __shfl_xor(v1, 8, 16);
          float gi = hiH ? v0 : w0;
          float gf = hiH ? w0 : v0;
          float gg = hiH ? v1 : w1;
          float go = hiH ? w1 : v1;
          float ii = sigm(gi), ff = sigm(gf), tg = tanhx(gg), oo = sigm(go);
          cst[nh][e] = ff * cst[nh][e] + ii * tg;
          float h = oo * tanhx(cst[nh][e]);
          u16 hb = (u16)((__builtin_bit_cast(u16, (f16)h) & 0xFFFEu) | P);
          int su = r * 16 + nh * 8 + u;
          if (hiH) {
            shp[su] = hb;
          } else {
            f16 hf = __builtin_bit_cast(f16, hb);
            f16 l16 = (f16)((h - (float)hf) * 1024.0f);
            slp[su] = (u16)((__builtin_bit_cast(u16, l16) & 0xFFFEu) | P);
          }
        }
      }
      __syncthreads();      // stage complete (only barrier this step)
      // ---- fire-and-forget coop store: 2x2KB contiguous, full-line ----
      {
        u16* bh = p_hi + (size_t)slot_w * SLOT + (size_t)c * 32768 + (size_t)sl * 1024;
        u16* bl = p_lo + (size_t)slot_w * SLOT + (size_t)c * 32768 + (size_t)sl * 1024;
#pragma unroll
        for (int i = tid; i < 512; i += 256) {
          int strm = i >> 8, pc = i & 255;
          const u16* src = (strm ? slp : shp) + pc * 4;
          st8((strm ? bl : bh) + pc * 4, *(const u64*)src);
        }
      }
      // no drain, no flag — data self-validates
    }
  } else {
    // ======== layer 1: q_s = LSTM(p_s, q_{s-1}) ========
    float b1c0[2], b1c1[2], wfv[2];
#pragma unroll
    for (int nh = 0; nh < 2; ++nh) {
      int base = sl * 16 + nh * 8 + u;
      b1c0[nh] = bias1[g01 * 512 + base];
      b1c1[nh] = bias1[(2 + g01) * 512 + base];
      wfv[nh] = wf[base];
    }
    float cst[2][4] = {{0.f,0.f,0.f,0.f},{0.f,0.f,0.f,0.f}};
    unsigned* prog_me = progc + sl * 32;
    const f16x8* wx_ = (const f16x8*)smem;
    const f16x8* wh_ = (const f16x8*)(smem + 65536);

    for (int t = 0; t < NT_; ++t) {
      const int slot_r = (t + RING - 1) & (RING - 1);   // q_{t-1}
      const int slot_w = t & (RING - 1);                // q_t / p_t
      f32x4 acc[4], accL[4];
#pragma unroll
      for (int t4 = 0; t4 < 4; ++t4) {
        acc[t4] = (f32x4){0.f,0.f,0.f,0.f};
        accL[t4] = (f32x4){0.f,0.f,0.f,0.f};
      }
      if (t) {
        // ---- fill q_{t-1} (parity ((t-1)>>4)&1) + ph1 ----
        const u16* aqh = (const u16*)q_hi + (size_t)slot_r * SLOT + (size_t)c * 32768 +
                         (qd >> 1) * 1024 + lr * 16 + (qd & 1) * 8;
        const u16* aql = (const u16*)q_lo + (size_t)slot_r * SLOT + (size_t)c * 32768 +
                         (qd >> 1) * 1024 + lr * 16 + (qd & 1) * 8;
        const u64 want = (((t - 1) >> 4) & 1) ? PMASK : 0ull;
        u64 wh_a[32], wl_a[32];
        for (;;) {
#pragma unroll
          for (int kt = 0; kt < 16; ++kt) {
            wh_a[2*kt]   = ld8a(aqh + kt * 2048);
            wh_a[2*kt+1] = ld8a(aqh + kt * 2048 + 4);
            wl_a[2*kt]   = ld8a(aql + kt * 2048);
            wl_a[2*kt+1] = ld8a(aql + kt * 2048 + 4);
          }
          bool ok = true;
#pragma unroll
          for (int i = 0; i < 32; ++i)
            ok &= ((wh_a[i] & PMASK) == want) & ((wl_a[i] & PMASK) == want);
          if (!~__ballot(ok)) break;
          __builtin_amdgcn_s_sleep(1);
        }
        asm volatile("" ::: "memory");
#pragma unroll
        for (int kt = 0; kt < 16; ++kt) {
          f16x8 Ah = frag(wh_a[2*kt], wh_a[2*kt+1]);
          f16x8 Al = frag(wl_a[2*kt], wl_a[2*kt+1]);
#pragma unroll
          for (int t4 = 0; t4 < 4; ++t4) {
            f16x8 bw = wh_[(t4 * 16 + kt) * 64 + ln];
            acc[t4]  = __builtin_amdgcn_mfma_f32_16x16x32_f16(Ah, bw, acc[t4], 0, 0, 0);
            accL[t4] = __builtin_amdgcn_mfma_f32_16x16x32_f16(Al, bw, accL[t4], 0, 0, 0);
          }
        }
      }
      // ---- fill p_t (parity (t>>4)&1; usually first-try) + ph2 ----
      {
        const u16* aph = (const u16*)p_hi + (size_t)slot_w * SLOT + (size_t)c * 32768 +
                         (qd >> 1) * 1024 + lr * 16 + (qd & 1) * 8;
        const u16* apl = (const u16*)p_lo + (size_t)slot_w * SLOT + (size_t)c * 32768 +
                         (qd >> 1) * 1024 + lr * 16 + (qd & 1) * 8;
        const u64 want = ((t >> 4) & 1) ? PMASK : 0ull;
        u64 wh_a[32], wl_a[32];
        for (;;) {
#pragma unroll
          for (int kt = 0; kt < 16; ++kt) {
            wh_a[2*kt]   = ld8a(aph + kt * 2048);
            wh_a[2*kt+1] = ld8a(aph + kt * 2048 + 4);
            wl_a[2*kt]   = ld8a(apl + kt * 2048);
            wl_a[2*kt+1] = ld8a(apl + kt * 2048 + 4);
          }
          bool ok = true;
#pragma unroll
          for (int i = 0; i < 32; ++i)
            ok &= ((wh_a[i] & PMASK) == want) & ((wl_a[i] & PMASK) == want);
          if (!~__ballot(ok)) break;
          __builtin_amdgcn_s_sleep(1);
        }
        asm volatile("" ::: "memory");
#pragma unroll
        for (int kt = 0; kt < 16; ++kt) {
          f16x8 Ah = frag(wh_a[2*kt], wh_a[2*kt+1]);
          f16x8 Al = frag(wl_a[2*kt], wl_a[2*kt+1]);
#pragma unroll
          for (int t4 = 0; t4 < 4; ++t4) {
            f16x8 bw = wx_[(t4 * 16 + kt) * 64 + ln];
            acc[t4]  = __builtin_amdgcn_mfma_f32_16x16x32_f16(Ah, bw, acc[t4], 0, 0, 0);
            accL[t4] = __builtin_amdgcn_mfma_f32_16x16x32_f16(Al, bw, accL[t4], 0, 0, 0);
          }
        }
      }
      // ---- epilogue -> double-buffered stage, parity-forced ----
      u16* shq = (u16*)(smem + 131072) + (t & 1) * 2048;
      u16* slq = shq + 1024;
      const u16 P = (u16)((t >> 4) & 1);
      float po[4];
#pragma unroll
      for (int e = 0; e < 4; ++e) {
        po[e] = 0.0f;
        int r = wv * 16 + qd * 4 + e;
#pragma unroll
        for (int nh = 0; nh < 2; ++nh) {
          float v0 = acc[nh*2+0][e] + accL[nh*2+0][e] * LO + b1c0[nh];   // i / f
          float v1 = acc[nh*2+1][e] + accL[nh*2+1][e] * LO + b1c1[nh];   // g / o
          float w0 = __shfl_xor(v0, 8, 16);
          float w1 = __shfl_xor(v1, 8, 16);
          float gi = hiH ? v0 : w0;
          float gf = hiH ? w0 : v0;
          float gg = hiH ? v1 : w1;
          float go = hiH ? w1 : v1;
          float ii = sigm(gi), ff = sigm(gf), tg = tanhx(gg), oo = sigm(go);
          cst[nh][e] = ff * cst[nh][e] + ii * tg;
          float h = oo * tanhx(cst[nh][e]);
          u16 hb = (u16)((__builtin_bit_cast(u16, (f16)h) & 0xFFFEu) | P);
          int su = r * 16 + nh * 8 + u;
          if (hiH) {
            shq[su] = hb;
          } else {
            f16 hf = __builtin_bit_cast(f16, hb);
            f16 l16 = (f16)((h - (float)hf) * 1024.0f);
            slq[su] = (u16)((__builtin_bit_cast(u16, l16) & 0xFFFEu) | P);
          }
          po[e] += hiH ? wfv[nh] * h : 0.0f;
        }
      }
      __syncthreads();      // stage complete (only barrier this step)
      // publish consumption progress (p_t validated by all waves pre-barrier)
      if (tid == 0) stf(prog_me, (unsigned)(t + 1));
      // ---- fire-and-forget coop store of q_t ----
      {
        u16* bh = q_hi + (size_t)slot_w * SLOT + (size_t)c * 32768 + (size_t)sl * 1024;
        u16* bl = q_lo + (size_t)slot_w * SLOT + (size_t)c * 32768 + (size_t)sl * 1024;
#pragma unroll
        for (int i = tid; i < 512; i += 256) {
          int strm = i >> 8, pc = i & 255;
          const u16* src = (strm ? slq : shq) + pc * 4;
          st8((strm ? bl : bh) + pc * 4, *(const u64*)src);
        }
      }
      // ---- deferred head-output reduce + atomic ----
#pragma unroll
      for (int e = 0; e < 4; ++e) {
        float r = po[e];
#pragma unroll
        for (int m = 1; m < 16; m <<= 1) r += __shfl_xor(r, m, 16);
        if (cl == 0)
          atomicAdd(part8 + (size_t)(sl & 7) * (NB * NT_) +
                        (size_t)(c * 64 + wv * 16 + qd * 4 + e) * NT_ + t, r);
      }
    }
  }
}

// ---------------------------------------------------------------------------
extern "C" void kernel_launch(void* const* d_in, const int* in_sizes, int n_in,
                              void* d_out, int out_size, void* d_ws, size_t ws_size,
                              hipStream_t stream) {
  (void)in_sizes; (void)n_in; (void)out_size; (void)ws_size;
  const float* inp = (const float*)d_in[0];
  const float* Wx0 = (const float*)d_in[1];
  const float* Wh0 = (const float*)d_in[2];
  const float* b0  = (const float*)d_in[3];
  const float* Wx1 = (const float*)d_in[4];
  const float* Wh1 = (const float*)d_in[5];
  const float* b1  = (const float*)d_in[6];
  const float* Wf  = (const float*)d_in[7];
  const float* bf  = (const float*)d_in[8];

  const size_t MB = 1u << 20;
  const size_t OFF_W    = 0;                 // 6 MiB tiled fp16 weights
  const size_t OFF_XT   = 6 * MB;            // 1 MiB
  const size_t OFF_PHI  = 7 * MB;            // 4 MiB (RING x 256 KB)
  const size_t OFF_PLO  = 11 * MB;
  const size_t OFF_QHI  = 15 * MB;
  const size_t OFF_QLO  = 19 * MB;
  const size_t OFF_PART = 23 * MB;           // 8 MiB
  const size_t OFF_PROG = 31 * MB;           // 16 KB progress lines

  char* ws = (char*)d_ws;
  f16* wsl = (f16*)(ws + OFF_W);
  float* xT = (float*)(ws + OFF_XT);
  u16* phi = (u16*)(ws + OFF_PHI);
  u16* plo = (u16*)(ws + OFF_PLO);
  u16* qhi = (u16*)(ws + OFF_QHI);
  u16* qlo = (u16*)(ws + OFF_QLO);
  float* part8 = (float*)(ws + OFF_PART);
  unsigned int* prog = (unsigned int*)(ws + OFF_PROG);
  float* out = (float*)d_out;

  (void)hipFuncSetAttribute((const void*)lstm_main,
                            hipFuncAttributeMaxDynamicSharedMemorySize, 139264);

  // transport rings -> 0xFF sentinel (parity 1 != epoch-0 parity 0);
  // partials + progress -> 0
  (void)hipMemsetAsync(ws + OFF_PHI, 0xFF, 16 * MB, stream);
  (void)hipMemsetAsync(ws + OFF_PART, 0, 8 * MB + 16384, stream);

  prep_xT<<<1024, 256, 0, stream>>>(inp, xT);
  prep_w<<<12288, 256, 0, stream>>>(Wh0, Wx1, Wh1, wsl);

  lstm_main<<<256, 256, 139264, stream>>>(xT, wsl, Wx0, b0, b1, Wf,
                                          phi, plo, qhi, qlo, prog, part8);

  reduce_out<<<1024, 256, 0, stream>>>(part8, bf, out);
}